// Round 14
// baseline (168.994 us; speedup 1.0000x reference)
//
#include <hip/hip_runtime.h>
#include <hip/hip_bf16.h>

#define B_  64
#define T_  1000
#define F_  140
#define D_  256
#define EPS_ 1e-5f

// time-chunking: tau=2 => v-influence decays 2^-step; W=8 warmup steps from
// v=0 reproduce the true LIF state to ~1e-3 abs — ~500x below the spike margin.
#define W2_ 8

// k3 chunking (many blocks, short chains)
#define CL_ 50
#define NC_ 20

// k12 chunking: 64 rows = 3 halo | 8 warm | 50 writes | 3 halo. row r <-> t = 50c-11+r.
#define CWR_ 50
#define NCH_ 20     // 50*20 = 1000 exactly
#define HST_ 256    // hbuf row stride (shorts): 64*256*2 = 32,768 B -> 5 blocks/CU
#define AST_ 168    // A row stride (shorts), K padded 140->160

typedef __attribute__((ext_vector_type(8))) short bf16x8;
typedef __attribute__((ext_vector_type(4))) short bf16x4;
typedef __attribute__((ext_vector_type(4))) float f32x4;
typedef unsigned long long u64;

static __device__ inline short f2bf(float f) {
  __hip_bfloat16 h = __float2bfloat16(f);
  return *reinterpret_cast<short*>(&h);
}
static __device__ inline float bf2f(short s) {
  unsigned int u = ((unsigned int)(unsigned short)s) << 16;
  return __uint_as_float(u);
}

// ---------------- K0: lwT transpose + pw_w -> MFMA B-fragment layout (global)
__global__ __launch_bounds__(256) void k0_prep(const float* __restrict__ lw,
                                               float* __restrict__ lwT,
                                               const float* __restrict__ pw,
                                               short* __restrict__ wfrag) {
  int i = blockIdx.x * 256 + threadIdx.x;
  if (i < 65536) {
    int e = i >> 8, d = i & 255;
    lwT[(size_t)d * D_ + e] = lw[(size_t)e * D_ + d];
  } else if (i < 65536 + 40960) {
    int j = i - 65536;
    int q = j & 7;
    int lane = (j >> 3) & 63;
    int rest = j >> 9;              // ntile*5 + kk
    int kk = rest % 5, ntile = rest / 5;
    int n = ntile * 16 + (lane & 15);
    int k = kk * 32 + (lane >> 4) * 8 + q;
    wfrag[j] = (k < F_) ? f2bf(pw[(size_t)n * F_ + k]) : (short)0;
  }
}

// ---------------- K12: fused pointwise-GEMM + depthwise conv + BN1 + LIF1 -> bits
// grid = (b, chunk). 256 threads / 4 waves. GEMM M=64 rows, N=256 (wave owns 64 n),
// K=160. A one-shot LDS stage; B frag-layout from global (L2), pipelined.
// bits layout: [b][dq][T] -> one coalesced store per wave at scan end.
__global__ __launch_bounds__(256, 5) void k12_fused(const float* __restrict__ x,
                                                    const short* __restrict__ wfrag,
                                                    const float* __restrict__ bias,
                                                    const float* __restrict__ dww,
                                                    const float* __restrict__ g1,
                                                    const float* __restrict__ b1,
                                                    const float* __restrict__ m1,
                                                    const float* __restrict__ v1,
                                                    u64* __restrict__ bits) {
  __shared__ short smem[64 * HST_];         // 32,768 B -> 5 blocks/CU
  short* Abuf = smem;                        // 64 x AST_, consumed before overlay
  short* hbuf = smem;                        // 64 x HST_
  const int b = blockIdx.x;
  const int c = blockIdx.y;
  const int tb = CWR_ * c - 11;              // row r <-> t = tb + r
  const int tid = threadIdx.x;
  const int lane = tid & 63, wv = tid >> 6;
  const int lr = lane & 15, quad = lane >> 4;

  // ---- A stage: 4 threads/row, float4 segments (36/36/36/32 floats), cvt bf16
  {
    const int arow = tid >> 2, aseg = tid & 3;
    const int ak0 = aseg * 36;
    const int anum4 = (aseg == 3) ? 8 : 9;
    const int ta = tb + arow;
    short* adst = Abuf + arow * AST_ + ak0;
    if (ta >= 0 && ta < T_) {
      const float* xrow = x + ((size_t)b * T_ + ta) * F_ + ak0;
#pragma unroll
      for (int q = 0; q < 9; q++) {
        if (q < anum4) {
          float4 av = *(const float4*)(xrow + q * 4);
          bf16x4 pk = {f2bf(av.x), f2bf(av.y), f2bf(av.z), f2bf(av.w)};
          *(bf16x4*)(adst + q * 4) = pk;
        }
      }
    } else {
      bf16x4 z = {0, 0, 0, 0};
#pragma unroll
      for (int q = 0; q < 9; q++)
        if (q < anum4) *(bf16x4*)(adst + q * 4) = z;
    }
    if (aseg == 3) {                         // zero-pad k in [140,160)
      bf16x4 z = {0, 0, 0, 0};
#pragma unroll
      for (int q = 0; q < 5; q++) *(bf16x4*)(adst + 32 + q * 4) = z;
    }
  }

  // first B fragments issued before the barrier (independent of LDS)
  const short* wfb = wfrag + (size_t)(wv * 4 * 5) * 512 + lane * 8;
  bf16x8 bfr[4];
#pragma unroll
  for (int j = 0; j < 4; j++)
    bfr[j] = *(const bf16x8*)(wfb + (size_t)(j * 5 + 0) * 512);
  __syncthreads();

  // ---- GEMM with pipelined B loads
  f32x4 acc[4][4] = {};
#pragma unroll
  for (int kk = 0; kk < 5; kk++) {
    bf16x8 bnext[4];
    if (kk < 4) {
#pragma unroll
      for (int j = 0; j < 4; j++)
        bnext[j] = *(const bf16x8*)(wfb + (size_t)(j * 5 + kk + 1) * 512);
    }
    bf16x8 af[4];
#pragma unroll
    for (int i = 0; i < 4; i++)
      af[i] = *(const bf16x8*)(Abuf + (i * 16 + lr) * AST_ + kk * 32 + quad * 8);
#pragma unroll
    for (int i = 0; i < 4; i++)
#pragma unroll
      for (int j = 0; j < 4; j++)
        acc[i][j] = __builtin_amdgcn_mfma_f32_16x16x32_bf16(af[i], bfr[j], acc[i][j], 0, 0, 0);
    if (kk < 4) {
#pragma unroll
      for (int j = 0; j < 4; j++) bfr[j] = bnext[j];
    }
  }
  __syncthreads();                           // A consumed; hbuf overlays

  // ---- epilogue: C + bias -> hbuf bf16; rows with t outside [0,T) -> 0
#pragma unroll
  for (int j = 0; j < 4; j++) {
    const int n = wv * 64 + j * 16 + lr;
    const float badd = bias[n];
#pragma unroll
    for (int i = 0; i < 4; i++) {
#pragma unroll
      for (int r = 0; r < 4; r++) {
        const int row = i * 16 + quad * 4 + r;
        const int t = tb + row;
        short val = (t >= 0 && t < T_) ? f2bf(acc[i][j][r] + badd) : (short)0;
        hbuf[row * HST_ + n] = val;
      }
    }
  }
  __syncthreads();

  // ---- depthwise conv (K=7) + BN1 + LIF1 scan: thread = d. 58 steps:
  // s<8 warmup (zero-rows for chunk 0 make it a no-op), s>=8 write i=s-8.
  {
    const int d = tid;
    const float scv = g1[d] * rsqrtf(v1[d] + EPS_);
    float w2[7];
#pragma unroll
    for (int k = 0; k < 7; k++) w2[k] = dww[d * 7 + k] * (0.5f * scv);
    const float sh2 = 0.5f * (b1[d] - m1[d] * scv);

    float win0 = bf2f(hbuf[0 * HST_ + d]);
    float win1 = bf2f(hbuf[1 * HST_ + d]);
    float win2 = bf2f(hbuf[2 * HST_ + d]);
    float win3 = bf2f(hbuf[3 * HST_ + d]);
    float win4 = bf2f(hbuf[4 * HST_ + d]);
    float win5 = bf2f(hbuf[5 * HST_ + d]);
    float v = 0.f;
    u64 mymask = 0;

#pragma unroll
    for (int s0 = 0; s0 < 56; s0 += 8) {
      float tap[8];
#pragma unroll
      for (int g = 0; g < 8; g++) tap[g] = bf2f(hbuf[(s0 + g + 6) * HST_ + d]);
#pragma unroll
      for (int g = 0; g < 8; g++) {
        const int s = s0 + g;
        float u2 = win0 * w2[0] + win1 * w2[1] + win2 * w2[2] + win3 * w2[3] +
                   win4 * w2[4] + win5 * w2[5] + tap[g] * w2[6] + sh2;
        v = 0.5f * v + u2;
        bool sp = (v >= 1.0f);
        if (s >= W2_) {
          u64 mask = __ballot(sp);
          if (lane == (s - W2_)) mymask = mask;
        }
        v = sp ? 0.f : v;
        win0 = win1; win1 = win2; win2 = win3; win3 = win4; win4 = win5; win5 = tap[g];
      }
    }
    {                                        // steps 56, 57
      float tap[2];
#pragma unroll
      for (int g = 0; g < 2; g++) tap[g] = bf2f(hbuf[(56 + g + 6) * HST_ + d]);
#pragma unroll
      for (int g = 0; g < 2; g++) {
        const int s = 56 + g;
        float u2 = win0 * w2[0] + win1 * w2[1] + win2 * w2[2] + win3 * w2[3] +
                   win4 * w2[4] + win5 * w2[5] + tap[g] * w2[6] + sh2;
        v = 0.5f * v + u2;
        bool sp = (v >= 1.0f);
        u64 mask = __ballot(sp);
        if (lane == (s - W2_)) mymask = mask;
        v = sp ? 0.f : v;
        win0 = win1; win1 = win2; win2 = win3; win3 = win4; win4 = win5; win5 = tap[g];
      }
    }
    const int tw0 = CWR_ * c;
    if (lane < CWR_)                         // 50x20 = 1000: never out of range
      bits[((size_t)b * 4 + wv) * T_ + tw0 + lane] = mymask;
  }
}

// ---------------- K3: sparse linear (spikes @ lin_w^T) + BN2 + LIF2 + residual
// bits layout [b][dq][T]: stage 4 contiguous segments to LDS. W=8 warmup.
__global__ __launch_bounds__(256) void k3_lin_lif(const u64* __restrict__ bits,
                                                  const float* __restrict__ lwT,
                                                  const float* __restrict__ g2,
                                                  const float* __restrict__ b2,
                                                  const float* __restrict__ m2,
                                                  const float* __restrict__ v2,
                                                  float* __restrict__ out) {
  __shared__ u64 sb[4 * 64];
  const int b = blockIdx.x;
  const int t0 = blockIdx.y * CL_;
  const int tstart = (t0 >= W2_) ? t0 - W2_ : 0;
  const int nwarm = t0 - tstart;            // 0 (chunk 0) or 8
  const int nsteps = nwarm + CL_;           // 50 or 58
  const int e = threadIdx.x;
  {
    const int dq = e >> 6, sidx = e & 63;
    const u64* src = bits + ((size_t)b * 4 + dq) * T_ + tstart;
    if (sidx < nsteps) sb[dq * 64 + sidx] = src[sidx];
  }
  __syncthreads();

  const float sc = g2[e] * rsqrtf(v2[e] + EPS_);
  const float shf = b2[e] - m2[e] * sc;
  const int eq = e >> 6, eb = e & 63;
  float v = 0.f;

  if (nwarm) {                              // fixed 8 warmup steps
#pragma unroll
    for (int s0 = 0; s0 < W2_; s0 += 4) {
      u64 a0[4], a1[4], a2[4], a3[4];
#pragma unroll
      for (int g = 0; g < 4; g++) {
        a0[g] = sb[0 * 64 + s0 + g]; a1[g] = sb[1 * 64 + s0 + g];
        a2[g] = sb[2 * 64 + s0 + g]; a3[g] = sb[3 * 64 + s0 + g];
      }
#pragma unroll
      for (int g = 0; g < 4; g++) {
        float u = shf;
        if (a0[g] | a1[g] | a2[g] | a3[g]) {   // wave-uniform
          float acc = 0.f;
          u64 mm;
          mm = a0[g]; while (mm) { int l = __builtin_ctzll(mm); mm &= mm - 1; acc += lwT[(size_t)(l) * D_ + e]; }
          mm = a1[g]; while (mm) { int l = __builtin_ctzll(mm); mm &= mm - 1; acc += lwT[(size_t)(64 + l) * D_ + e]; }
          mm = a2[g]; while (mm) { int l = __builtin_ctzll(mm); mm &= mm - 1; acc += lwT[(size_t)(128 + l) * D_ + e]; }
          mm = a3[g]; while (mm) { int l = __builtin_ctzll(mm); mm &= mm - 1; acc += lwT[(size_t)(192 + l) * D_ + e]; }
          u = acc * sc + shf;
        }
        v = 0.5f * (v + u);
        v = (v >= 1.0f) ? 0.f : v;
      }
    }
  }
  float* op = out + ((size_t)t0 * B_ + b) * D_ + e;
  const size_t ts = (size_t)B_ * D_;
#pragma unroll
  for (int s0 = 0; s0 < CL_; s0 += 5) {     // fixed 50 write steps
    u64 a0[5], a1[5], a2[5], a3[5];
#pragma unroll
    for (int g = 0; g < 5; g++) {
      const int s = nwarm + s0 + g;
      a0[g] = sb[0 * 64 + s]; a1[g] = sb[1 * 64 + s];
      a2[g] = sb[2 * 64 + s]; a3[g] = sb[3 * 64 + s];
    }
#pragma unroll
    for (int g = 0; g < 5; g++) {
      float u = shf;
      if (a0[g] | a1[g] | a2[g] | a3[g]) {
        float acc = 0.f;
        u64 mm;
        mm = a0[g]; while (mm) { int l = __builtin_ctzll(mm); mm &= mm - 1; acc += lwT[(size_t)(l) * D_ + e]; }
        mm = a1[g]; while (mm) { int l = __builtin_ctzll(mm); mm &= mm - 1; acc += lwT[(size_t)(64 + l) * D_ + e]; }
        mm = a2[g]; while (mm) { int l = __builtin_ctzll(mm); mm &= mm - 1; acc += lwT[(size_t)(128 + l) * D_ + e]; }
        mm = a3[g]; while (mm) { int l = __builtin_ctzll(mm); mm &= mm - 1; acc += lwT[(size_t)(192 + l) * D_ + e]; }
        u = acc * sc + shf;
      }
      v = 0.5f * (v + u);
      bool sp = (v >= 1.0f);
      u64 myw = (eq == 0) ? a0[g] : (eq == 1) ? a1[g] : (eq == 2) ? a2[g] : a3[g];
      float s1 = (float)((myw >> eb) & 1ull);
      op[(size_t)(s0 + g) * ts] = (sp ? 1.0f : 0.0f) + s1;
      v = sp ? 0.f : v;
    }
  }
}

extern "C" void kernel_launch(void* const* d_in, const int* in_sizes, int n_in,
                              void* d_out, int out_size, void* d_ws, size_t ws_size,
                              hipStream_t stream) {
  const float* x    = (const float*)d_in[0];
  const float* pw_w = (const float*)d_in[1];
  const float* pw_b = (const float*)d_in[2];
  const float* dw_w = (const float*)d_in[3];
  const float* g1   = (const float*)d_in[4];
  const float* b1   = (const float*)d_in[5];
  const float* m1   = (const float*)d_in[6];
  const float* v1   = (const float*)d_in[7];
  const float* lw   = (const float*)d_in[8];
  const float* g2   = (const float*)d_in[9];
  const float* b2   = (const float*)d_in[10];
  const float* m2   = (const float*)d_in[11];
  const float* v2   = (const float*)d_in[12];
  float* out = (float*)d_out;

  char* ws = (char*)d_ws;
  u64* bits = (u64*)ws;                                    // 2,048,000 B
  float* lwT = (float*)(ws + 2048000);                     //   262,144 B
  short* wfrag = (short*)(ws + 2048000 + 262144);          //    81,920 B

  k0_prep<<<(65536 + 40960 + 255) / 256, 256, 0, stream>>>(lw, lwT, pw_w, wfrag);
  dim3 g_k12(B_, NCH_);
  k12_fused<<<g_k12, 256, 0, stream>>>(x, wfrag, pw_b, dw_w, g1, b1, m1, v1, bits);
  dim3 g_k3(B_, NC_);
  k3_lin_lif<<<g_k3, 256, 0, stream>>>(bits, lwT, g2, b2, m2, v2, out);
}

// Round 15
// 147.948 us; speedup vs baseline: 1.1423x; 1.1423x over previous
//
#include <hip/hip_runtime.h>
#include <hip/hip_bf16.h>

#define B_  64
#define T_  1000
#define F_  140
#define D_  256
#define EPS_ 1e-5f

// time-chunking: tau=2 => v-influence decays 2^-step; W=8 warmup steps from
// v=0 reproduce the true LIF state to ~1e-3 abs — ~500x below the spike margin
// (v sits >=5 sigma from V_TH; absmax=0 held across all rounds incl. bf16 jitter).
#define W2_ 8

// k3 chunking (many blocks, short chains)
#define CL_ 50
#define NC_ 20

// k12 chunking: 64 rows = 3 halo | 8 warm | 50 writes | 3 halo. row r <-> t = 50c-11+r.
#define CWR_ 50
#define NCH_ 20     // 50*20 = 1000 exactly
#define HST_ 268    // hbuf row stride (shorts): conflict-free b16 reads/writes
#define AST_ 168    // A row stride (shorts), K padded 140->160

typedef __attribute__((ext_vector_type(8))) short bf16x8;
typedef __attribute__((ext_vector_type(4))) short bf16x4;
typedef __attribute__((ext_vector_type(4))) float f32x4;
typedef unsigned long long u64;

static __device__ inline short f2bf(float f) {
  __hip_bfloat16 h = __float2bfloat16(f);
  return *reinterpret_cast<short*>(&h);
}
static __device__ inline float bf2f(short s) {
  unsigned int u = ((unsigned int)(unsigned short)s) << 16;
  return __uint_as_float(u);
}

// ---------------- K0: lwT transpose + pw_w -> MFMA B-fragment layout (global)
__global__ __launch_bounds__(256) void k0_prep(const float* __restrict__ lw,
                                               float* __restrict__ lwT,
                                               const float* __restrict__ pw,
                                               short* __restrict__ wfrag) {
  int i = blockIdx.x * 256 + threadIdx.x;
  if (i < 65536) {
    int e = i >> 8, d = i & 255;
    lwT[(size_t)d * D_ + e] = lw[(size_t)e * D_ + d];
  } else if (i < 65536 + 40960) {
    int j = i - 65536;
    int q = j & 7;
    int lane = (j >> 3) & 63;
    int rest = j >> 9;              // ntile*5 + kk
    int kk = rest % 5, ntile = rest / 5;
    int n = ntile * 16 + (lane & 15);
    int k = kk * 32 + (lane >> 4) * 8 + q;
    wfrag[j] = (k < F_) ? f2bf(pw[(size_t)n * F_ + k]) : (short)0;
  }
}

// ---------------- K12: fused pointwise-GEMM + depthwise conv + BN1 + LIF1 -> bits
// grid = (b, chunk). 256 threads / 4 waves. GEMM M=64 rows, N=256 (wave owns 64 n),
// K=160. A one-shot LDS stage; B frag-layout from global (L2), pipelined.
// bits layout: [b][dq][T] -> one coalesced store per wave at scan end.
// NOTE: launch_bounds min-waves MUST stay 4 — 5 caps VGPR<64 and spills the
// MFMA accumulators to scratch (R14: +80MB scratch traffic, 2.3x slower).
__global__ __launch_bounds__(256, 4) void k12_fused(const float* __restrict__ x,
                                                    const short* __restrict__ wfrag,
                                                    const float* __restrict__ bias,
                                                    const float* __restrict__ dww,
                                                    const float* __restrict__ g1,
                                                    const float* __restrict__ b1,
                                                    const float* __restrict__ m1,
                                                    const float* __restrict__ v1,
                                                    u64* __restrict__ bits) {
  __shared__ short smem[64 * HST_];         // 34,304 B -> 4 blocks/CU
  short* Abuf = smem;                        // 64 x AST_, consumed before overlay
  short* hbuf = smem;                        // 64 x HST_
  const int b = blockIdx.x;
  const int c = blockIdx.y;
  const int tb = CWR_ * c - 11;              // row r <-> t = tb + r
  const int tid = threadIdx.x;
  const int lane = tid & 63, wv = tid >> 6;
  const int lr = lane & 15, quad = lane >> 4;

  // ---- A stage: 4 threads/row, float4 segments (36/36/36/32 floats), cvt bf16
  {
    const int arow = tid >> 2, aseg = tid & 3;
    const int ak0 = aseg * 36;
    const int anum4 = (aseg == 3) ? 8 : 9;
    const int ta = tb + arow;
    short* adst = Abuf + arow * AST_ + ak0;
    if (ta >= 0 && ta < T_) {
      const float* xrow = x + ((size_t)b * T_ + ta) * F_ + ak0;
#pragma unroll
      for (int q = 0; q < 9; q++) {
        if (q < anum4) {
          float4 av = *(const float4*)(xrow + q * 4);
          bf16x4 pk = {f2bf(av.x), f2bf(av.y), f2bf(av.z), f2bf(av.w)};
          *(bf16x4*)(adst + q * 4) = pk;
        }
      }
    } else {
      bf16x4 z = {0, 0, 0, 0};
#pragma unroll
      for (int q = 0; q < 9; q++)
        if (q < anum4) *(bf16x4*)(adst + q * 4) = z;
    }
    if (aseg == 3) {                         // zero-pad k in [140,160)
      bf16x4 z = {0, 0, 0, 0};
#pragma unroll
      for (int q = 0; q < 5; q++) *(bf16x4*)(adst + 32 + q * 4) = z;
    }
  }

  // first B fragments issued before the barrier (independent of LDS)
  const short* wfb = wfrag + (size_t)(wv * 4 * 5) * 512 + lane * 8;
  bf16x8 bfr[4];
#pragma unroll
  for (int j = 0; j < 4; j++)
    bfr[j] = *(const bf16x8*)(wfb + (size_t)(j * 5 + 0) * 512);
  __syncthreads();

  // ---- GEMM with pipelined B loads
  f32x4 acc[4][4] = {};
#pragma unroll
  for (int kk = 0; kk < 5; kk++) {
    bf16x8 bnext[4];
    if (kk < 4) {
#pragma unroll
      for (int j = 0; j < 4; j++)
        bnext[j] = *(const bf16x8*)(wfb + (size_t)(j * 5 + kk + 1) * 512);
    }
    bf16x8 af[4];
#pragma unroll
    for (int i = 0; i < 4; i++)
      af[i] = *(const bf16x8*)(Abuf + (i * 16 + lr) * AST_ + kk * 32 + quad * 8);
#pragma unroll
    for (int i = 0; i < 4; i++)
#pragma unroll
      for (int j = 0; j < 4; j++)
        acc[i][j] = __builtin_amdgcn_mfma_f32_16x16x32_bf16(af[i], bfr[j], acc[i][j], 0, 0, 0);
    if (kk < 4) {
#pragma unroll
      for (int j = 0; j < 4; j++) bfr[j] = bnext[j];
    }
  }
  __syncthreads();                           // A consumed; hbuf overlays

  // ---- epilogue: C + bias -> hbuf bf16; rows with t outside [0,T) -> 0
#pragma unroll
  for (int j = 0; j < 4; j++) {
    const int n = wv * 64 + j * 16 + lr;
    const float badd = bias[n];
#pragma unroll
    for (int i = 0; i < 4; i++) {
#pragma unroll
      for (int r = 0; r < 4; r++) {
        const int row = i * 16 + quad * 4 + r;
        const int t = tb + row;
        short val = (t >= 0 && t < T_) ? f2bf(acc[i][j][r] + badd) : (short)0;
        hbuf[row * HST_ + n] = val;
      }
    }
  }
  __syncthreads();

  // ---- depthwise conv (K=7) + BN1 + LIF1 scan: thread = d. 58 steps:
  // s<8 warmup (zero-rows for chunk 0 make it a no-op), s>=8 write i=s-8.
  {
    const int d = tid;
    const float scv = g1[d] * rsqrtf(v1[d] + EPS_);
    float w2[7];
#pragma unroll
    for (int k = 0; k < 7; k++) w2[k] = dww[d * 7 + k] * (0.5f * scv);
    const float sh2 = 0.5f * (b1[d] - m1[d] * scv);

    float win0 = bf2f(hbuf[0 * HST_ + d]);
    float win1 = bf2f(hbuf[1 * HST_ + d]);
    float win2 = bf2f(hbuf[2 * HST_ + d]);
    float win3 = bf2f(hbuf[3 * HST_ + d]);
    float win4 = bf2f(hbuf[4 * HST_ + d]);
    float win5 = bf2f(hbuf[5 * HST_ + d]);
    float v = 0.f;
    u64 mymask = 0;

#pragma unroll
    for (int s0 = 0; s0 < 56; s0 += 8) {
      float tap[8];
#pragma unroll
      for (int g = 0; g < 8; g++) tap[g] = bf2f(hbuf[(s0 + g + 6) * HST_ + d]);
#pragma unroll
      for (int g = 0; g < 8; g++) {
        const int s = s0 + g;
        float u2 = win0 * w2[0] + win1 * w2[1] + win2 * w2[2] + win3 * w2[3] +
                   win4 * w2[4] + win5 * w2[5] + tap[g] * w2[6] + sh2;
        v = 0.5f * v + u2;
        bool sp = (v >= 1.0f);
        if (s >= W2_) {
          u64 mask = __ballot(sp);
          if (lane == (s - W2_)) mymask = mask;
        }
        v = sp ? 0.f : v;
        win0 = win1; win1 = win2; win2 = win3; win3 = win4; win4 = win5; win5 = tap[g];
      }
    }
    {                                        // steps 56, 57
      float tap[2];
#pragma unroll
      for (int g = 0; g < 2; g++) tap[g] = bf2f(hbuf[(56 + g + 6) * HST_ + d]);
#pragma unroll
      for (int g = 0; g < 2; g++) {
        const int s = 56 + g;
        float u2 = win0 * w2[0] + win1 * w2[1] + win2 * w2[2] + win3 * w2[3] +
                   win4 * w2[4] + win5 * w2[5] + tap[g] * w2[6] + sh2;
        v = 0.5f * v + u2;
        bool sp = (v >= 1.0f);
        u64 mask = __ballot(sp);
        if (lane == (s - W2_)) mymask = mask;
        v = sp ? 0.f : v;
        win0 = win1; win1 = win2; win2 = win3; win3 = win4; win4 = win5; win5 = tap[g];
      }
    }
    const int tw0 = CWR_ * c;
    if (lane < CWR_)                         // 50x20 = 1000: never out of range
      bits[((size_t)b * 4 + wv) * T_ + tw0 + lane] = mymask;
  }
}

// ---------------- K3: sparse linear (spikes @ lin_w^T) + BN2 + LIF2 + residual
// bits layout [b][dq][T]: stage 4 contiguous segments to LDS. W=8 warmup.
__global__ __launch_bounds__(256) void k3_lin_lif(const u64* __restrict__ bits,
                                                  const float* __restrict__ lwT,
                                                  const float* __restrict__ g2,
                                                  const float* __restrict__ b2,
                                                  const float* __restrict__ m2,
                                                  const float* __restrict__ v2,
                                                  float* __restrict__ out) {
  __shared__ u64 sb[4 * 64];
  const int b = blockIdx.x;
  const int t0 = blockIdx.y * CL_;
  const int tstart = (t0 >= W2_) ? t0 - W2_ : 0;
  const int nwarm = t0 - tstart;            // 0 (chunk 0) or 8
  const int nsteps = nwarm + CL_;           // 50 or 58
  const int e = threadIdx.x;
  {
    const int dq = e >> 6, sidx = e & 63;
    const u64* src = bits + ((size_t)b * 4 + dq) * T_ + tstart;
    if (sidx < nsteps) sb[dq * 64 + sidx] = src[sidx];
  }
  __syncthreads();

  const float sc = g2[e] * rsqrtf(v2[e] + EPS_);
  const float shf = b2[e] - m2[e] * sc;
  const int eq = e >> 6, eb = e & 63;
  float v = 0.f;

  if (nwarm) {                              // fixed 8 warmup steps
#pragma unroll
    for (int s0 = 0; s0 < W2_; s0 += 4) {
      u64 a0[4], a1[4], a2[4], a3[4];
#pragma unroll
      for (int g = 0; g < 4; g++) {
        a0[g] = sb[0 * 64 + s0 + g]; a1[g] = sb[1 * 64 + s0 + g];
        a2[g] = sb[2 * 64 + s0 + g]; a3[g] = sb[3 * 64 + s0 + g];
      }
#pragma unroll
      for (int g = 0; g < 4; g++) {
        float u = shf;
        if (a0[g] | a1[g] | a2[g] | a3[g]) {   // wave-uniform
          float acc = 0.f;
          u64 mm;
          mm = a0[g]; while (mm) { int l = __builtin_ctzll(mm); mm &= mm - 1; acc += lwT[(size_t)(l) * D_ + e]; }
          mm = a1[g]; while (mm) { int l = __builtin_ctzll(mm); mm &= mm - 1; acc += lwT[(size_t)(64 + l) * D_ + e]; }
          mm = a2[g]; while (mm) { int l = __builtin_ctzll(mm); mm &= mm - 1; acc += lwT[(size_t)(128 + l) * D_ + e]; }
          mm = a3[g]; while (mm) { int l = __builtin_ctzll(mm); mm &= mm - 1; acc += lwT[(size_t)(192 + l) * D_ + e]; }
          u = acc * sc + shf;
        }
        v = 0.5f * (v + u);
        v = (v >= 1.0f) ? 0.f : v;
      }
    }
  }
  float* op = out + ((size_t)t0 * B_ + b) * D_ + e;
  const size_t ts = (size_t)B_ * D_;
#pragma unroll
  for (int s0 = 0; s0 < CL_; s0 += 5) {     // fixed 50 write steps
    u64 a0[5], a1[5], a2[5], a3[5];
#pragma unroll
    for (int g = 0; g < 5; g++) {
      const int s = nwarm + s0 + g;
      a0[g] = sb[0 * 64 + s]; a1[g] = sb[1 * 64 + s];
      a2[g] = sb[2 * 64 + s]; a3[g] = sb[3 * 64 + s];
    }
#pragma unroll
    for (int g = 0; g < 5; g++) {
      float u = shf;
      if (a0[g] | a1[g] | a2[g] | a3[g]) {
        float acc = 0.f;
        u64 mm;
        mm = a0[g]; while (mm) { int l = __builtin_ctzll(mm); mm &= mm - 1; acc += lwT[(size_t)(l) * D_ + e]; }
        mm = a1[g]; while (mm) { int l = __builtin_ctzll(mm); mm &= mm - 1; acc += lwT[(size_t)(64 + l) * D_ + e]; }
        mm = a2[g]; while (mm) { int l = __builtin_ctzll(mm); mm &= mm - 1; acc += lwT[(size_t)(128 + l) * D_ + e]; }
        mm = a3[g]; while (mm) { int l = __builtin_ctzll(mm); mm &= mm - 1; acc += lwT[(size_t)(192 + l) * D_ + e]; }
        u = acc * sc + shf;
      }
      v = 0.5f * (v + u);
      bool sp = (v >= 1.0f);
      u64 myw = (eq == 0) ? a0[g] : (eq == 1) ? a1[g] : (eq == 2) ? a2[g] : a3[g];
      float s1 = (float)((myw >> eb) & 1ull);
      op[(size_t)(s0 + g) * ts] = (sp ? 1.0f : 0.0f) + s1;
      v = sp ? 0.f : v;
    }
  }
}

extern "C" void kernel_launch(void* const* d_in, const int* in_sizes, int n_in,
                              void* d_out, int out_size, void* d_ws, size_t ws_size,
                              hipStream_t stream) {
  const float* x    = (const float*)d_in[0];
  const float* pw_w = (const float*)d_in[1];
  const float* pw_b = (const float*)d_in[2];
  const float* dw_w = (const float*)d_in[3];
  const float* g1   = (const float*)d_in[4];
  const float* b1   = (const float*)d_in[5];
  const float* m1   = (const float*)d_in[6];
  const float* v1   = (const float*)d_in[7];
  const float* lw   = (const float*)d_in[8];
  const float* g2   = (const float*)d_in[9];
  const float* b2   = (const float*)d_in[10];
  const float* m2   = (const float*)d_in[11];
  const float* v2   = (const float*)d_in[12];
  float* out = (float*)d_out;

  char* ws = (char*)d_ws;
  u64* bits = (u64*)ws;                                    // 2,048,000 B
  float* lwT = (float*)(ws + 2048000);                     //   262,144 B
  short* wfrag = (short*)(ws + 2048000 + 262144);          //    81,920 B

  k0_prep<<<(65536 + 40960 + 255) / 256, 256, 0, stream>>>(lw, lwT, pw_w, wfrag);
  dim3 g_k12(B_, NCH_);
  k12_fused<<<g_k12, 256, 0, stream>>>(x, wfrag, pw_b, dw_w, g1, b1, m1, v1, bits);
  dim3 g_k3(B_, NC_);
  k3_lin_lif<<<g_k3, 256, 0, stream>>>(bits, lwT, g2, b2, m2, v2, out);
}